// Round 12
// baseline (36728.070 us; speedup 1.0000x reference)
//
#include <hip/hip_runtime.h>

#define H 51
#define E 4              // batch elements per block (weight traffic amortization)

__device__ __forceinline__ float rl_(float v, int lane) {
    return __builtin_bit_cast(float, __builtin_amdgcn_readlane(__builtin_bit_cast(int, v), lane));
}
template<int CTRL>
__device__ __forceinline__ float qb_(float v) {   // quad_perm broadcast (DPP, VALU pipe)
    return __builtin_bit_cast(float, __builtin_amdgcn_update_dpp(
        0, __builtin_bit_cast(int, v), CTRL, 0xf, 0xf, true));
}

// act = A * rcp(1 + exp2(m2*x)) + B   (sigmoid: m2=-log2e,A=1,B=0 ; tanh: m2=2log2e,A=-2,B=1)
__device__ __forceinline__ float act_(float x, float m2, float A, float B) {
    const float e = __builtin_amdgcn_exp2f(m2 * x);
    const float r = __builtin_amdgcn_rcpf(1.f + e);
    return fmaf(A, r, B);
}
__device__ __forceinline__ float tanh_(float c) {
    const float e = __builtin_amdgcn_exp2f(2.885390082f * c);
    const float r = __builtin_amdgcn_rcpf(1.f + e);
    return fmaf(-2.f, r, 1.f);
}

#define FOR51(M) \
 M(0) M(1) M(2) M(3) M(4) M(5) M(6) M(7) M(8) M(9) \
 M(10) M(11) M(12) M(13) M(14) M(15) M(16) M(17) M(18) M(19) \
 M(20) M(21) M(22) M(23) M(24) M(25) M(26) M(27) M(28) M(29) \
 M(30) M(31) M(32) M(33) M(34) M(35) M(36) M(37) M(38) M(39) \
 M(40) M(41) M(42) M(43) M(44) M(45) M(46) M(47) M(48) M(49) M(50)

// one weight load feeds 4 fmas (one per batch element). The transient asm pin
// (single def, volatile, 1-reg live range) stops remat from duplicating the
// load per use while giving the allocator nothing worth spilling.
#define MACK(k) { \
    float wv = Wmp[k]; \
    asm volatile("" : "+v"(wv)); \
    acc0 = fmaf(rl_(hv0, k), wv, acc0); \
    acc1 = fmaf(rl_(hv1, k), wv, acc1); \
    acc2 = fmaf(rl_(hv2, k), wv, acc2); \
    acc3 = fmaf(rl_(hv3, k), wv, acc3); }

#define GATECOMB(PRE, CC, HN) { \
    const float a_ = act_(PRE, m2A, Aa, Ba); \
    const float si = qb_<0x00>(a_); \
    const float sf = qb_<0x55>(a_); \
    const float tg = qb_<0xAA>(a_); \
    const float so = qb_<0xFF>(a_); \
    CC = fmaf(sf, CC, si * tg); \
    HN = so * tanh_(CC); }

__global__ __launch_bounds__(768)
void lstm_seq_kernel(const float* __restrict__ x,
                     const float* __restrict__ Wih1, const float* __restrict__ Whh1,
                     const float* __restrict__ bih1, const float* __restrict__ bhh1,
                     const float* __restrict__ Wih2, const float* __restrict__ Whh2,
                     const float* __restrict__ bih2, const float* __restrict__ bhh2,
                     const float* __restrict__ fcw, const float* __restrict__ fcb,
                     float* __restrict__ out, int T, int future)
{
    const int b   = blockIdx.x;        // handles batch elements E*b .. E*b+3
    const int tid = threadIdx.x;
    const int l   = tid & 63;          // lane
    const int w   = tid >> 6;          // wave 0..11
    const int grp = w >> 2;            // 0: Whh1+act1+c1 | 1: Whh2 partial | 2: Wih2+act2+c2+fc
    const int j   = w & 3;             // wave within group
    const int uq  = l >> 2;            // unit-within-wave 0..15 (13 valid)
    const int g   = l & 3;             // gate 0:i 1:f 2:g 3:o
    const int u   = 13 * j + uq;       // unit 0..50
    const bool act_lane = (uq < 13) && (u < H);
    const bool g0lane   = act_lane && (g == 0);
    const int row = act_lane ? (g * H + u) : 0;

    extern __shared__ float xld[];              // [E*T] x rows for this block
    __shared__ float h1s[2][E][64];             // double-buffered h1 per element
    __shared__ float h2s[2][E][64];
    __shared__ float hh2buf[E][220];            // Whh2.h2 partials, idx = 52*j + l
    __shared__ __align__(16) float fcp[E][4];   // fc partials [element][wave j]

    for (int i = tid; i < E * T; i += 768) {
        const int e = i / T, ii = i - e * T;
        xld[i] = x[(size_t)(E * b + e) * T + ii];
    }
    if (tid < 2 * E * 64) { ((float*)h1s)[tid] = 0.f; ((float*)h2s)[tid] = 0.f; }
    if (tid < E * 4) ((float*)fcp)[tid] = 0.f;

    const float* Wm  = (grp == 0) ? Whh1 : ((grp == 1) ? Whh2 : Wih2);
    const float* Wmp = Wm + (size_t)row * H;    // this lane's weight row

    const float wx1   = (grp == 0 && act_lane) ? Wih1[row] : 0.f;
    const float bias1 = (grp == 0 && act_lane) ? (bih1[row] + bhh1[row]) : 0.f;
    const float bias2 = (grp == 2 && act_lane) ? (bih2[row] + bhh2[row]) : 0.f;
    const float fcu   = (grp == 2 && g0lane) ? fcw[u] : 0.f;
    const float fcb_l = fcb[0];

    const float m2A = (g == 2) ? 2.885390082f : -1.442695041f;
    const float Aa  = act_lane ? ((g == 2) ? -2.f : 1.f) : 0.f;
    const float Ba  = (act_lane && g == 2) ? 1.f : 0.f;

    float cc0 = 0.f, cc1 = 0.f, cc2 = 0.f, cc3 = 0.f;  // c1 (grp0) / c2 (grp2) per element
    __syncthreads();

    const int TT = T + future;
    for (int t = 0; t < TT; ++t) {
        const int p = t & 1, q = p ^ 1;

        // ---- out(t-1) per element from fc partials ----
        float o_0 = 0.f, o_1 = 0.f, o_2 = 0.f, o_3 = 0.f;
        if (t > 0) {
            const float4 f0 = *(const float4*)fcp[0];
            const float4 f1 = *(const float4*)fcp[1];
            const float4 f2 = *(const float4*)fcp[2];
            const float4 f3 = *(const float4*)fcp[3];
            o_0 = (f0.x + f0.y) + (f0.z + f0.w) + fcb_l;
            o_1 = (f1.x + f1.y) + (f1.z + f1.w) + fcb_l;
            o_2 = (f2.x + f2.y) + (f2.z + f2.w) + fcb_l;
            o_3 = (f3.x + f3.y) + (f3.z + f3.w) + fcb_l;
            if (tid == 0) out[(size_t)(E * b + 0) * TT + (t - 1)] = o_0;
            if (tid == 1) out[(size_t)(E * b + 1) * TT + (t - 1)] = o_1;
            if (tid == 2) out[(size_t)(E * b + 2) * TT + (t - 1)] = o_2;
            if (tid == 3) out[(size_t)(E * b + 3) * TT + (t - 1)] = o_3;
        }

        // ================= phase B =================
        if (grp == 0) {
            const float xt0 = (t < T) ? xld[0 * T + t] : o_0;
            const float xt1 = (t < T) ? xld[1 * T + t] : o_1;
            const float xt2 = (t < T) ? xld[2 * T + t] : o_2;
            const float xt3 = (t < T) ? xld[3 * T + t] : o_3;
            const float hv0 = h1s[q][0][l];
            const float hv1 = h1s[q][1][l];
            const float hv2 = h1s[q][2][l];
            const float hv3 = h1s[q][3][l];
            float acc0 = 0.f, acc1 = 0.f, acc2 = 0.f, acc3 = 0.f;
            FOR51(MACK)
            const float pre0 = bias1 + fmaf(wx1, xt0, acc0);
            const float pre1 = bias1 + fmaf(wx1, xt1, acc1);
            const float pre2 = bias1 + fmaf(wx1, xt2, acc2);
            const float pre3 = bias1 + fmaf(wx1, xt3, acc3);
            float hn0, hn1, hn2, hn3;
            GATECOMB(pre0, cc0, hn0)
            GATECOMB(pre1, cc1, hn1)
            GATECOMB(pre2, cc2, hn2)
            GATECOMB(pre3, cc3, hn3)
            if (g0lane) {
                h1s[p][0][u] = hn0; h1s[p][1][u] = hn1;
                h1s[p][2][u] = hn2; h1s[p][3][u] = hn3;
            }
        } else if (grp == 1) {
            const float hv0 = h2s[q][0][l];
            const float hv1 = h2s[q][1][l];
            const float hv2 = h2s[q][2][l];
            const float hv3 = h2s[q][3][l];
            float acc0 = 0.f, acc1 = 0.f, acc2 = 0.f, acc3 = 0.f;
            FOR51(MACK)
            if (act_lane) {
                hh2buf[0][52 * j + l] = acc0; hh2buf[1][52 * j + l] = acc1;
                hh2buf[2][52 * j + l] = acc2; hh2buf[3][52 * j + l] = acc3;
            }
        }
        __syncthreads();                       // barrier 1: h1(t), hh2buf visible

        // ================= phase C =================
        if (grp == 2) {
            const float hv0 = h1s[p][0][l];
            const float hv1 = h1s[p][1][l];
            const float hv2 = h1s[p][2][l];
            const float hv3 = h1s[p][3][l];
            float acc0 = 0.f, acc1 = 0.f, acc2 = 0.f, acc3 = 0.f;
            FOR51(MACK)
            float pre0 = bias2 + acc0, pre1 = bias2 + acc1;
            float pre2 = bias2 + acc2, pre3 = bias2 + acc3;
            if (act_lane) {
                pre0 += hh2buf[0][52 * j + l]; pre1 += hh2buf[1][52 * j + l];
                pre2 += hh2buf[2][52 * j + l]; pre3 += hh2buf[3][52 * j + l];
            }
            float hn0, hn1, hn2, hn3;
            GATECOMB(pre0, cc0, hn0)
            GATECOMB(pre1, cc1, hn1)
            GATECOMB(pre2, cc2, hn2)
            GATECOMB(pre3, cc3, hn3)
            if (g0lane) {
                h2s[p][0][u] = hn0; h2s[p][1][u] = hn1;
                h2s[p][2][u] = hn2; h2s[p][3][u] = hn3;
            }
            // fc partials per element (g==0 lanes carry fcw[u]*h2n)
            float pv0 = g0lane ? hn0 * fcu : 0.f;
            float pv1 = g0lane ? hn1 * fcu : 0.f;
            float pv2 = g0lane ? hn2 * fcu : 0.f;
            float pv3 = g0lane ? hn3 * fcu : 0.f;
            #pragma unroll
            for (int off = 4; off <= 32; off <<= 1) {
                pv0 += __shfl_xor(pv0, off, 64);
                pv1 += __shfl_xor(pv1, off, 64);
                pv2 += __shfl_xor(pv2, off, 64);
                pv3 += __shfl_xor(pv3, off, 64);
            }
            if (l == 0) {
                fcp[0][j] = pv0; fcp[1][j] = pv1;
                fcp[2][j] = pv2; fcp[3][j] = pv3;
            }
        }
        __syncthreads();                       // barrier 2: h2(t), fcp visible
    }

    // final outputs
    {
        const float4 f0 = *(const float4*)fcp[0];
        const float4 f1 = *(const float4*)fcp[1];
        const float4 f2 = *(const float4*)fcp[2];
        const float4 f3 = *(const float4*)fcp[3];
        if (tid == 0) out[(size_t)(E * b + 0) * TT + (TT - 1)] = (f0.x + f0.y) + (f0.z + f0.w) + fcb_l;
        if (tid == 1) out[(size_t)(E * b + 1) * TT + (TT - 1)] = (f1.x + f1.y) + (f1.z + f1.w) + fcb_l;
        if (tid == 2) out[(size_t)(E * b + 2) * TT + (TT - 1)] = (f2.x + f2.y) + (f2.z + f2.w) + fcb_l;
        if (tid == 3) out[(size_t)(E * b + 3) * TT + (TT - 1)] = (f3.x + f3.y) + (f3.z + f3.w) + fcb_l;
    }
}

extern "C" void kernel_launch(void* const* d_in, const int* in_sizes, int n_in,
                              void* d_out, int out_size, void* d_ws, size_t ws_size,
                              hipStream_t stream) {
    const float* x    = (const float*)d_in[0];
    const float* Wih1 = (const float*)d_in[1];
    const float* Whh1 = (const float*)d_in[2];
    const float* bih1 = (const float*)d_in[3];
    const float* bhh1 = (const float*)d_in[4];
    const float* Wih2 = (const float*)d_in[5];
    const float* Whh2 = (const float*)d_in[6];
    const float* bih2 = (const float*)d_in[7];
    const float* bhh2 = (const float*)d_in[8];
    const float* fcw  = (const float*)d_in[9];
    const float* fcb  = (const float*)d_in[10];
    float* out = (float*)d_out;

    const int B  = 256;                 // fixed by setup (H=51 hardcoded)
    const int T  = in_sizes[0] / B;     // 2048
    const int TT = out_size / B;        // T + future
    const int future = TT - T;

    const size_t shmem = (size_t)E * T * sizeof(float);   // 32 KB at T=2048
    hipLaunchKernelGGL(lstm_seq_kernel, dim3(B / E), dim3(768), shmem, stream,
                       x, Wih1, Whh1, bih1, bhh1, Wih2, Whh2, bih2, bhh2,
                       fcw, fcb, out, T, future);
}

// Round 13
// 7941.924 us; speedup vs baseline: 4.6246x; 4.6246x over previous
//
#include <hip/hip_runtime.h>

#define H 51
#define E 2              // batch elements per block: optimum of max(issue, L2 traffic)

__device__ __forceinline__ float rl_(float v, int lane) {
    return __builtin_bit_cast(float, __builtin_amdgcn_readlane(__builtin_bit_cast(int, v), lane));
}
template<int CTRL>
__device__ __forceinline__ float qb_(float v) {   // quad_perm broadcast (DPP, VALU pipe)
    return __builtin_bit_cast(float, __builtin_amdgcn_update_dpp(
        0, __builtin_bit_cast(int, v), CTRL, 0xf, 0xf, true));
}

// act = A * rcp(1 + exp2(m2*x)) + B   (sigmoid: m2=-log2e,A=1,B=0 ; tanh: m2=2log2e,A=-2,B=1)
__device__ __forceinline__ float act_(float x, float m2, float A, float B) {
    const float e = __builtin_amdgcn_exp2f(m2 * x);
    const float r = __builtin_amdgcn_rcpf(1.f + e);
    return fmaf(A, r, B);
}
__device__ __forceinline__ float tanh_(float c) {
    const float e = __builtin_amdgcn_exp2f(2.885390082f * c);
    const float r = __builtin_amdgcn_rcpf(1.f + e);
    return fmaf(-2.f, r, 1.f);
}

#define FOR51(M) \
 M(0) M(1) M(2) M(3) M(4) M(5) M(6) M(7) M(8) M(9) \
 M(10) M(11) M(12) M(13) M(14) M(15) M(16) M(17) M(18) M(19) \
 M(20) M(21) M(22) M(23) M(24) M(25) M(26) M(27) M(28) M(29) \
 M(30) M(31) M(32) M(33) M(34) M(35) M(36) M(37) M(38) M(39) \
 M(40) M(41) M(42) M(43) M(44) M(45) M(46) M(47) M(48) M(49) M(50)

// one weight load feeds E=2 fmas. NO pins, NO volatile (R12 post-mortem:
// volatile asm serialized the loads). Adjacent uses -> a single (possibly
// rematerialized) load per iteration; loads batch freely.
#define MACK(k) { \
    const float wv = Wmp[k]; \
    acc0 = fmaf(rl_(hv0, k), wv, acc0); \
    acc1 = fmaf(rl_(hv1, k), wv, acc1); }

#define GATECOMB(PRE, CC, HN) { \
    const float a_ = act_(PRE, m2A, Aa, Ba); \
    const float si = qb_<0x00>(a_); \
    const float sf = qb_<0x55>(a_); \
    const float tg = qb_<0xAA>(a_); \
    const float so = qb_<0xFF>(a_); \
    CC = fmaf(sf, CC, si * tg); \
    HN = so * tanh_(CC); }

__global__ __launch_bounds__(768)
void lstm_seq_kernel(const float* __restrict__ x,
                     const float* __restrict__ Wih1, const float* __restrict__ Whh1,
                     const float* __restrict__ bih1, const float* __restrict__ bhh1,
                     const float* __restrict__ Wih2, const float* __restrict__ Whh2,
                     const float* __restrict__ bih2, const float* __restrict__ bhh2,
                     const float* __restrict__ fcw, const float* __restrict__ fcb,
                     float* __restrict__ out, int T, int future)
{
    const int b   = blockIdx.x;        // handles batch elements E*b, E*b+1
    const int tid = threadIdx.x;
    const int l   = tid & 63;          // lane
    const int w   = tid >> 6;          // wave 0..11
    const int grp = w >> 2;            // 0: Whh1+act1+c1 | 1: Whh2 partial | 2: Wih2+act2+c2+fc
    const int j   = w & 3;             // wave within group
    const int uq  = l >> 2;            // unit-within-wave 0..15 (13 valid)
    const int g   = l & 3;             // gate 0:i 1:f 2:g 3:o
    const int u   = 13 * j + uq;       // unit 0..50
    const bool act_lane = (uq < 13) && (u < H);
    const bool g0lane   = act_lane && (g == 0);
    const int row = act_lane ? (g * H + u) : 0;

    extern __shared__ float xld[];              // [E*T] x rows for this block
    __shared__ float h1s[2][E][64];             // double-buffered h1 per element
    __shared__ float h2s[2][E][64];
    __shared__ float hh2buf[E][220];            // Whh2.h2 partials, idx = 52*j + l
    __shared__ __align__(16) float fcp[E][4];   // fc partials [element][wave j]

    for (int i = tid; i < E * T; i += 768) {
        const int e = i / T, ii = i - e * T;
        xld[i] = x[(size_t)(E * b + e) * T + ii];
    }
    if (tid < 2 * E * 64) { ((float*)h1s)[tid] = 0.f; ((float*)h2s)[tid] = 0.f; }
    if (tid < E * 4) ((float*)fcp)[tid] = 0.f;

    const float* Wm  = (grp == 0) ? Whh1 : ((grp == 1) ? Whh2 : Wih2);
    const float* Wmp = Wm + (size_t)row * H;    // this lane's weight row

    const float wx1   = (grp == 0 && act_lane) ? Wih1[row] : 0.f;
    const float bias1 = (grp == 0 && act_lane) ? (bih1[row] + bhh1[row]) : 0.f;
    const float bias2 = (grp == 2 && act_lane) ? (bih2[row] + bhh2[row]) : 0.f;
    const float fcu   = (grp == 2 && g0lane) ? fcw[u] : 0.f;
    const float fcb_l = fcb[0];

    const float m2A = (g == 2) ? 2.885390082f : -1.442695041f;
    const float Aa  = act_lane ? ((g == 2) ? -2.f : 1.f) : 0.f;
    const float Ba  = (act_lane && g == 2) ? 1.f : 0.f;

    float cc0 = 0.f, cc1 = 0.f;        // c1 (grp0) / c2 (grp2) per element
    __syncthreads();

    const int TT = T + future;
    for (int t = 0; t < TT; ++t) {
        const int p = t & 1, q = p ^ 1;

        // ---- out(t-1) per element from fc partials ----
        float o_0 = 0.f, o_1 = 0.f;
        if (t > 0) {
            const float4 f0 = *(const float4*)fcp[0];
            const float4 f1 = *(const float4*)fcp[1];
            o_0 = (f0.x + f0.y) + (f0.z + f0.w) + fcb_l;
            o_1 = (f1.x + f1.y) + (f1.z + f1.w) + fcb_l;
            if (tid == 0) out[(size_t)(E * b + 0) * TT + (t - 1)] = o_0;
            if (tid == 1) out[(size_t)(E * b + 1) * TT + (t - 1)] = o_1;
        }

        // ================= phase B =================
        if (grp == 0) {
            const float xt0 = (t < T) ? xld[0 * T + t] : o_0;
            const float xt1 = (t < T) ? xld[1 * T + t] : o_1;
            const float hv0 = h1s[q][0][l];
            const float hv1 = h1s[q][1][l];
            float acc0 = 0.f, acc1 = 0.f;
            FOR51(MACK)
            const float pre0 = bias1 + fmaf(wx1, xt0, acc0);
            const float pre1 = bias1 + fmaf(wx1, xt1, acc1);
            float hn0, hn1;
            GATECOMB(pre0, cc0, hn0)
            GATECOMB(pre1, cc1, hn1)
            if (g0lane) { h1s[p][0][u] = hn0; h1s[p][1][u] = hn1; }
        } else if (grp == 1) {
            const float hv0 = h2s[q][0][l];
            const float hv1 = h2s[q][1][l];
            float acc0 = 0.f, acc1 = 0.f;
            FOR51(MACK)
            if (act_lane) {
                hh2buf[0][52 * j + l] = acc0;
                hh2buf[1][52 * j + l] = acc1;
            }
        }
        __syncthreads();                       // barrier 1: h1(t), hh2buf visible

        // ================= phase C =================
        if (grp == 2) {
            const float hv0 = h1s[p][0][l];
            const float hv1 = h1s[p][1][l];
            float acc0 = 0.f, acc1 = 0.f;
            FOR51(MACK)
            float pre0 = bias2 + acc0, pre1 = bias2 + acc1;
            if (act_lane) {
                pre0 += hh2buf[0][52 * j + l];
                pre1 += hh2buf[1][52 * j + l];
            }
            float hn0, hn1;
            GATECOMB(pre0, cc0, hn0)
            GATECOMB(pre1, cc1, hn1)
            if (g0lane) { h2s[p][0][u] = hn0; h2s[p][1][u] = hn1; }

            // fc partials per element (g==0 lanes carry fcw[u]*h2n)
            float pv0 = g0lane ? hn0 * fcu : 0.f;
            float pv1 = g0lane ? hn1 * fcu : 0.f;
            #pragma unroll
            for (int off = 4; off <= 32; off <<= 1) {
                pv0 += __shfl_xor(pv0, off, 64);
                pv1 += __shfl_xor(pv1, off, 64);
            }
            if (l == 0) { fcp[0][j] = pv0; fcp[1][j] = pv1; }
        }
        __syncthreads();                       // barrier 2: h2(t), fcp visible
    }

    // final outputs
    {
        const float4 f0 = *(const float4*)fcp[0];
        const float4 f1 = *(const float4*)fcp[1];
        if (tid == 0) out[(size_t)(E * b + 0) * TT + (TT - 1)] = (f0.x + f0.y) + (f0.z + f0.w) + fcb_l;
        if (tid == 1) out[(size_t)(E * b + 1) * TT + (TT - 1)] = (f1.x + f1.y) + (f1.z + f1.w) + fcb_l;
    }
}

extern "C" void kernel_launch(void* const* d_in, const int* in_sizes, int n_in,
                              void* d_out, int out_size, void* d_ws, size_t ws_size,
                              hipStream_t stream) {
    const float* x    = (const float*)d_in[0];
    const float* Wih1 = (const float*)d_in[1];
    const float* Whh1 = (const float*)d_in[2];
    const float* bih1 = (const float*)d_in[3];
    const float* bhh1 = (const float*)d_in[4];
    const float* Wih2 = (const float*)d_in[5];
    const float* Whh2 = (const float*)d_in[6];
    const float* bih2 = (const float*)d_in[7];
    const float* bhh2 = (const float*)d_in[8];
    const float* fcw  = (const float*)d_in[9];
    const float* fcb  = (const float*)d_in[10];
    float* out = (float*)d_out;

    const int B  = 256;                 // fixed by setup (H=51 hardcoded)
    const int T  = in_sizes[0] / B;     // 2048
    const int TT = out_size / B;        // T + future
    const int future = TT - T;

    const size_t shmem = (size_t)E * T * sizeof(float);   // 16 KB at T=2048
    hipLaunchKernelGGL(lstm_seq_kernel, dim3(B / E), dim3(768), shmem, stream,
                       x, Wih1, Whh1, bih1, bhh1, Wih2, Whh2, bih2, bhh2,
                       fcw, fcb, out, T, future);
}

// Round 14
// 2635.104 us; speedup vs baseline: 13.9380x; 3.0139x over previous
//
#include <hip/hip_runtime.h>

#define H 51
#define WREG 32           // weights k=0..31 in registers (R9: proven resident, VGPR 76)
#define TAILK 19          // weights k=32..50 in LDS, lane-major conflict-free layout

__device__ __forceinline__ float rl_(float v, int lane) {
    return __builtin_bit_cast(float, __builtin_amdgcn_readlane(__builtin_bit_cast(int, v), lane));
}
template<int CTRL>
__device__ __forceinline__ float qb_(float v) {   // quad_perm broadcast (DPP, VALU pipe)
    return __builtin_bit_cast(float, __builtin_amdgcn_update_dpp(
        0, __builtin_bit_cast(int, v), CTRL, 0xf, 0xf, true));
}

// act = A * rcp(1 + exp2(m2*x)) + B   (sigmoid: m2=-log2e,A=1,B=0 ; tanh: m2=2log2e,A=-2,B=1)
__device__ __forceinline__ float act_(float x, float m2, float A, float B) {
    const float e = __builtin_amdgcn_exp2f(m2 * x);
    const float r = __builtin_amdgcn_rcpf(1.f + e);
    return fmaf(A, r, B);
}
__device__ __forceinline__ float tanh_(float c) {
    const float e = __builtin_amdgcn_exp2f(2.885390082f * c);
    const float r = __builtin_amdgcn_rcpf(1.f + e);
    return fmaf(-2.f, r, 1.f);
}

#define FOR32(M) \
 M(0) M(1) M(2) M(3) M(4) M(5) M(6) M(7) M(8) M(9) \
 M(10) M(11) M(12) M(13) M(14) M(15) M(16) M(17) M(18) M(19) \
 M(20) M(21) M(22) M(23) M(24) M(25) M(26) M(27) M(28) M(29) M(30) M(31)

// M(k, k%4): round-robin accumulators, k ascending (fma order = rounds 5-13)
#define FOR32_RR(M) \
 M(0,0) M(1,1) M(2,2) M(3,3) M(4,0) M(5,1) M(6,2) M(7,3) \
 M(8,0) M(9,1) M(10,2) M(11,3) M(12,0) M(13,1) M(14,2) M(15,3) \
 M(16,0) M(17,1) M(18,2) M(19,3) M(20,0) M(21,1) M(22,2) M(23,3) \
 M(24,0) M(25,1) M(26,2) M(27,3) M(28,0) M(29,1) M(30,2) M(31,3)

// tail k = 32+kk, acc = (32+kk)%4 = kk%4  -> continues the same round-robin
#define FORTAIL(M) \
 M(0,0) M(1,1) M(2,2) M(3,3) M(4,0) M(5,1) M(6,2) M(7,3) \
 M(8,0) M(9,1) M(10,2) M(11,3) M(12,0) M(13,1) M(14,2) M(15,3) \
 M(16,0) M(17,1) M(18,2)

__global__ __launch_bounds__(768)    // default occupancy target: the exact config
                                     // under which R9's 32-scalar slice stayed
                                     // resident (VGPR 76, no pins, no min-waves)
void lstm_seq_kernel(const float* __restrict__ x,
                     const float* __restrict__ Wih1, const float* __restrict__ Whh1,
                     const float* __restrict__ bih1, const float* __restrict__ bhh1,
                     const float* __restrict__ Wih2, const float* __restrict__ Whh2,
                     const float* __restrict__ bih2, const float* __restrict__ bhh2,
                     const float* __restrict__ fcw, const float* __restrict__ fcb,
                     float* __restrict__ out, int T, int future)
{
    const int b   = blockIdx.x;
    const int tid = threadIdx.x;
    const int l   = tid & 63;          // lane
    const int w   = tid >> 6;          // wave 0..11
    const int grp = w >> 2;            // 0: Whh1+act1+c1 | 1: Whh2 partial | 2: Wih2+act2+c2+fc
    const int j   = w & 3;             // wave within group
    const int uq  = l >> 2;            // unit-within-wave 0..15 (13 valid)
    const int g   = l & 3;             // gate 0:i 1:f 2:g 3:o
    const int u   = 13 * j + uq;       // unit 0..50
    const bool act_lane = (uq < 13) && (u < H);
    const bool g0lane   = act_lane && (g == 0);
    const int row = act_lane ? (g * H + u) : 0;     // clamped: inactive lanes use row 0

    // tail weights, LANE-MAJOR: wlds[((m*4+j)*TAILK + kk)*64 + l].
    // A tail read is ds_read_b32 at base+kk*256 with consecutive lanes on
    // consecutive dwords -> banks = l%32, exactly 2 lanes/bank = conflict-free
    // (m136 stride-1 case). No wide reads, no stride arithmetic.
    __shared__ float wlds[3 * 4 * TAILK * 64];  // 58368 B
    __shared__ float h1s[2][64];                // double-buffered h1 (pad zeros)
    __shared__ float h2s[2][64];
    __shared__ float hh2buf[220];               // Whh2.h2 partial, idx = 52*j + l
    __shared__ __align__(16) float fcp[4];      // per-wave fc partial sums

    // ---- stage tail into LDS (one-time) ----
    for (int i = tid; i < 3 * 4 * TAILK * 64; i += 768) {
        const int l2  = i & 63;
        const int t2  = i >> 6;            // (m*4 + jj)*TAILK + kk
        const int kk  = t2 % TAILK;
        const int mj  = t2 / TAILK;        // 0..11
        const int jj  = mj & 3;
        const int m   = mj >> 2;
        const int uq2 = l2 >> 2, g2 = l2 & 3, u2 = 13 * jj + uq2;
        const bool al = (uq2 < 13) && (u2 < H);
        const int r2  = al ? (g2 * H + u2) : 0;
        const float* W = (m == 0) ? Whh1 : ((m == 1) ? Whh2 : Wih2);
        wlds[i] = al ? W[r2 * H + WREG + kk] : 0.f;
    }
    if (tid < 64) { h1s[0][tid] = 0.f; h1s[1][tid] = 0.f;
                    h2s[0][tid] = 0.f; h2s[1][tid] = 0.f; }
    if (tid < 4) fcp[tid] = 0.f;

    // ---- register slice: weights k=0..31 as named scalars (R9 config) ----
    const float* Wm = (grp == 0) ? Whh1 : ((grp == 1) ? Whh2 : Wih2);
    const int rb = row * H;
    #define DECLW(k) float wt_##k = Wm[rb + k];
    FOR32(DECLW)

    const float* wtail = &wlds[((grp * 4 + j) * TAILK) * 64 + l];

    // per-row constants
    const float wx1   = (grp == 0 && act_lane) ? Wih1[row] : 0.f;
    const float bias1 = (grp == 0 && act_lane) ? (bih1[row] + bhh1[row]) : 0.f;
    const float bias2 = (grp == 2 && act_lane) ? (bih2[row] + bhh2[row]) : 0.f;
    const float fcu   = (grp == 2 && g0lane) ? fcw[u] : 0.f;
    const float fcb_l = fcb[0];

    // activation constants per gate lane (grp 0 and 2)
    const float m2A = (g == 2) ? 2.885390082f : -1.442695041f;
    const float Aa  = act_lane ? ((g == 2) ? -2.f : 1.f) : 0.f;
    const float Ba  = (act_lane && g == 2) ? 1.f : 0.f;

    float cc = 0.f;                    // c1 (grp0) / c2 (grp2), quad-replicated
    float xt_pre = (grp == 0) ? x[(size_t)b * T] : 0.f;   // software prefetch of x[t]

    __syncthreads();

    // MAC macros: register slice k=0..31, LDS tail k=32..50
    #define MR(k, jj2) a##jj2 = fmaf(rl_(hv, k), wt_##k, a##jj2);
    #define MT(kk, jj2) a##jj2 = fmaf(rl_(hv, 32 + kk), wtail[kk * 64], a##jj2);

    const int TT = T + future;
    for (int t = 0; t < TT; ++t) {
        const int p = t & 1, q = p ^ 1;

        // ---- out(t-1) from fc partials (all threads compute o; tid0 stores) ----
        float o = 0.f;
        if (t > 0) {
            const float4 f = *(const float4*)fcp;
            o = (f.x + f.y) + (f.z + f.w) + fcb_l;
            if (tid == 0) out[(size_t)b * TT + (t - 1)] = o;
        }

        // ================= phase B =================
        if (grp == 0) {
            // full layer 1: pre1 -> gates (DPP quad) -> c1 -> h1(t)
            const float xt = (t < T) ? xt_pre : o;
            if (t + 1 < T) xt_pre = x[(size_t)b * T + t + 1];   // prefetch next x
            const float hv = h1s[q][l];
            float a0 = 0.f, a1 = 0.f, a2 = 0.f, a3 = 0.f;
            FOR32_RR(MR)
            FORTAIL(MT)
            const float pre1 = bias1 + fmaf(wx1, xt, (a0 + a1) + (a2 + a3));
            const float a = act_(pre1, m2A, Aa, Ba);
            const float si = qb_<0x00>(a);
            const float sf = qb_<0x55>(a);
            const float tg = qb_<0xAA>(a);
            const float so = qb_<0xFF>(a);
            cc = fmaf(sf, cc, si * tg);
            const float h1n = so * tanh_(cc);
            if (g0lane) h1s[p][u] = h1n;
        } else if (grp == 1) {
            // hh2 = Whh2[row,:] . h2(t-1)
            const float hv = h2s[q][l];
            float a0 = 0.f, a1 = 0.f, a2 = 0.f, a3 = 0.f;
            FOR32_RR(MR)
            FORTAIL(MT)
            if (act_lane) hh2buf[52 * j + l] = (a0 + a1) + (a2 + a3);
        }
        __syncthreads();                       // barrier 1: h1(t), hh2buf visible

        // ================= phase C =================
        if (grp == 2) {
            const float hv = h1s[p][l];
            float a0 = 0.f, a1 = 0.f, a2 = 0.f, a3 = 0.f;
            FOR32_RR(MR)
            FORTAIL(MT)
            const float hh2 = act_lane ? hh2buf[52 * j + l] : 0.f;
            const float pre2 = bias2 + hh2 + ((a0 + a1) + (a2 + a3));
            const float a = act_(pre2, m2A, Aa, Ba);
            const float si = qb_<0x00>(a);
            const float sf = qb_<0x55>(a);
            const float tg = qb_<0xAA>(a);
            const float so = qb_<0xFF>(a);
            cc = fmaf(sf, cc, si * tg);
            const float h2n = so * tanh_(cc);
            if (g0lane) h2s[p][u] = h2n;

            // fc partial for this wave's 13 units
            float pv = g0lane ? h2n * fcu : 0.f;
            pv += __shfl_xor(pv, 4, 64);
            pv += __shfl_xor(pv, 8, 64);
            pv += __shfl_xor(pv, 16, 64);
            pv += __shfl_xor(pv, 32, 64);
            if (l == 0) fcp[j] = pv;
        }
        __syncthreads();                       // barrier 2: h2(t), fcp visible
    }

    if (tid == 0) {
        const float4 f = *(const float4*)fcp;
        out[(size_t)b * TT + (TT - 1)] = (f.x + f.y) + (f.z + f.w) + fcb_l;
    }
}

extern "C" void kernel_launch(void* const* d_in, const int* in_sizes, int n_in,
                              void* d_out, int out_size, void* d_ws, size_t ws_size,
                              hipStream_t stream) {
    const float* x    = (const float*)d_in[0];
    const float* Wih1 = (const float*)d_in[1];
    const float* Whh1 = (const float*)d_in[2];
    const float* bih1 = (const float*)d_in[3];
    const float* bhh1 = (const float*)d_in[4];
    const float* Wih2 = (const float*)d_in[5];
    const float* Whh2 = (const float*)d_in[6];
    const float* bih2 = (const float*)d_in[7];
    const float* bhh2 = (const float*)d_in[8];
    const float* fcw  = (const float*)d_in[9];
    const float* fcb  = (const float*)d_in[10];
    float* out = (float*)d_out;

    const int B  = 256;                 // fixed by setup (H=51 hardcoded)
    const int T  = in_sizes[0] / B;     // 2048
    const int TT = out_size / B;        // T + future
    const int future = TT - T;

    hipLaunchKernelGGL(lstm_seq_kernel, dim3(B), dim3(768), 0, stream,
                       x, Wih1, Whh1, bih1, bhh1, Wih2, Whh2, bih2, bhh2,
                       fcw, fcb, out, T, future);
}